// Round 4
// baseline (45835.291 us; speedup 1.0000x reference)
//
#include <hip/hip_runtime.h>
#include <math.h>

typedef short s8v __attribute__((ext_vector_type(8)));
typedef float f32x4 __attribute__((ext_vector_type(4)));

// ---------- helpers ----------
__device__ inline float sigm(float x) { return 1.0f / (1.0f + expf(-x)); }
__device__ inline float dot4(const float4 a, const float4 b) {
  return a.x*b.x + a.y*b.y + a.z*b.z + a.w*b.w;
}
__device__ inline float wsum(float v) {
#pragma unroll
  for (int o = 32; o > 0; o >>= 1) v += __shfl_xor(v, o, 64);
  return v;
}
__device__ inline short f2bf(float f) {
  unsigned int u = __float_as_uint(f);
  unsigned int r = u + 0x7FFFu + ((u >> 16) & 1u);
  return (short)(r >> 16);
}
__device__ inline float bf2f(short h) {
  return __uint_as_float(((unsigned int)(unsigned short)h) << 16);
}
// split store: v = hi + lo (each bf16), lo captures the residual
__device__ inline void storesplit(float v, short* __restrict__ hi,
                                  short* __restrict__ lo, size_t idx) {
  short h = f2bf(v);
  hi[idx] = h;
  lo[idx] = f2bf(v - bf2f(h));
}

// wave GEMM single-bf16: C[64m x 16n], A[64xK] rows=m, B rows=n (k-contig)
template<int LD, int KS>
__device__ __forceinline__ void gemm4(const short* __restrict__ A,
                                      const short* __restrict__ B,
                                      f32x4 acc[4], int lane) {
  int off = (lane & 15) * LD + ((lane >> 4) * 8);
#pragma unroll 4
  for (int kb = 0; kb < KS; kb++) {
    int ko = off + kb*32;
    s8v bb = *(const s8v*)(B + ko);
#pragma unroll
    for (int m = 0; m < 4; m++) {
      s8v aa = *(const s8v*)(A + ko + m*16*LD);
      acc[m] = __builtin_amdgcn_mfma_f32_16x16x32_bf16(aa, bb, acc[m], 0,0,0);
    }
  }
}

// wave GEMM split-bf16 (3-term): fp32-grade precision
template<int LD, int KS>
__device__ __forceinline__ void gemm4s(const short* __restrict__ Ah,
                                       const short* __restrict__ Al,
                                       const short* __restrict__ Bh,
                                       const short* __restrict__ Bl,
                                       f32x4 acc[4], int lane) {
  int off = (lane & 15) * LD + ((lane >> 4) * 8);
#pragma unroll 2
  for (int kb = 0; kb < KS; kb++) {
    int ko = off + kb*32;
    s8v bh = *(const s8v*)(Bh + ko);
    s8v bl = *(const s8v*)(Bl + ko);
#pragma unroll
    for (int m = 0; m < 4; m++) {
      s8v ah = *(const s8v*)(Ah + ko + m*16*LD);
      s8v al = *(const s8v*)(Al + ko + m*16*LD);
      acc[m] = __builtin_amdgcn_mfma_f32_16x16x32_bf16(ah, bh, acc[m], 0,0,0);
      acc[m] = __builtin_amdgcn_mfma_f32_16x16x32_bf16(al, bh, acc[m], 0,0,0);
      acc[m] = __builtin_amdgcn_mfma_f32_16x16x32_bf16(ah, bl, acc[m], 0,0,0);
    }
  }
}

// ---------- weight prep (once per call) ----------
__global__ void kprep_g(const float* __restrict__ Wih, const float* __restrict__ Whh,
                        short* __restrict__ WgH, short* __restrict__ WgL) {
  int j = blockIdx.y, k = blockIdx.x*256 + threadIdx.x;
  if (k < 1792) {
    float v = (k < 768) ? Wih[(size_t)j*768 + k] : Whh[(size_t)j*1024 + (k-768)];
    storesplit(v, WgH, WgL, (size_t)j*1792 + k);
  }
}
__global__ void kprep_p(const float* __restrict__ Wp, short* __restrict__ W) {
  int j = blockIdx.y, k = blockIdx.x*256 + threadIdx.x;
  W[(size_t)j*1280 + k] = f2bf(Wp[(size_t)j*1280 + k]);
}
__global__ void kprep_h(const float* __restrict__ Wrk, const float* __restrict__ Wwk,
                        const float* __restrict__ Wev, const float* __restrict__ Wws,
                        short* __restrict__ WhH, short* __restrict__ WhL) {
  int j = blockIdx.y, k = blockIdx.x*256 + threadIdx.x;
  float v;
  if (j < 256)      v = Wrk[(size_t)j*1024 + k];
  else if (j < 512) v = Wwk[(size_t)(j-256)*1024 + k];
  else if (j < 768) v = Wev[(size_t)(j-512)*1024 + k];
  else if (j < 772) v = Wws[(size_t)(j-768)*1024 + k];
  else v = 0.f;
  storesplit(v, WhH, WhL, (size_t)j*1024 + k);
}
__global__ void kprep_q(const float* __restrict__ aw, short* __restrict__ WH,
                        short* __restrict__ WL) {
  int i = blockIdx.x*64 + threadIdx.x;
  storesplit(aw[i], WH, WL, i);
}

// ---------- prologue: xin for t=0 (rc=0) ----------
__global__ __launch_bounds__(256) void k_prep0(
    const float* __restrict__ x_emb, const float* __restrict__ in_g,
    const float* __restrict__ in_b, short* __restrict__ inbH,
    short* __restrict__ inbL)
{
  __shared__ float rs[4], rq[4];
  int b = blockIdx.x, tid = threadIdx.x, lane = tid & 63, wid = tid >> 6;
  float v3[3]; float s = 0.f, sq = 0.f;
#pragma unroll
  for (int i = 0; i < 3; i++) {
    int k = tid + i * 256;
    float v = (k < 512) ? x_emb[(size_t)b * 256 * 512 + k] : 0.f;
    v3[i] = v; s += v; sq += v * v;
  }
  s = wsum(s); sq = wsum(sq);
  if (lane == 0) { rs[wid] = s; rq[wid] = sq; }
  __syncthreads();
  float ts = rs[0]+rs[1]+rs[2]+rs[3], tq = rq[0]+rq[1]+rq[2]+rq[3];
  float mu = ts / 768.f, var = tq / 768.f - mu * mu;
  float rstd = rsqrtf(var + 1e-5f);
#pragma unroll
  for (int i = 0; i < 3; i++) {
    int k = tid + i * 256;
    storesplit((v3[i] - mu) * rstd * in_g[k] + in_b[k], inbH, inbL, b*1792 + k);
  }
}

// ---------- k1: logits(t-1) | qkv(t) | gates(t) ----------
// grid 144: [0,64) gates, [64,128) qkv, [128,144) logits
__global__ __launch_bounds__(256) void k1(
    const short* __restrict__ inbH, const short* __restrict__ inbL,
    const short* __restrict__ WgH, const short* __restrict__ WgL,
    const short* __restrict__ membH, const short* __restrict__ membL,
    const short* __restrict__ WqH, const short* __restrict__ WqL,
    const float* __restrict__ attn_b,
    const short* __restrict__ pob16, const short* __restrict__ Wp16,
    const float* __restrict__ b_proj,
    float* __restrict__ gates, float* __restrict__ qkv,
    float* __restrict__ outs, int t)
{
  int bid = blockIdx.x, tid = threadIdx.x, lane = tid & 63, w = tid >> 6;
  if (bid < 64) {            // gates: C[64b][64j] tile jt=bid, K=1792
    if (t >= 256) return;
    f32x4 acc[4] = {};
    size_t boff = (size_t)(bid*64 + w*16) * 1792;
    gemm4s<1792, 56>(inbH, inbL, WgH + boff, WgL + boff, acc, lane);
    int j = bid*64 + w*16 + (lane & 15);
#pragma unroll
    for (int ms = 0; ms < 4; ms++)
#pragma unroll
      for (int r = 0; r < 4; r++) {
        int b = ms*16 + (lane>>4)*4 + r;
        gates[b*4096 + j] = acc[ms][r];
      }
  } else if (bid < 128) {    // qkv for b=bid-64: C[128m][192j], K=64 (split)
    if (t >= 256) return;
    int b = bid - 64;
    const short* Ah = membH + (size_t)b * 8192;
    const short* Al = membL + (size_t)b * 8192;
    int ao = (w*32 + (lane & 15)) * 64 + (lane >> 4) * 8;
    s8v ah00 = *(const s8v*)(Ah + ao);
    s8v ah01 = *(const s8v*)(Ah + ao + 32);
    s8v ah10 = *(const s8v*)(Ah + ao + 16*64);
    s8v ah11 = *(const s8v*)(Ah + ao + 16*64 + 32);
    s8v al00 = *(const s8v*)(Al + ao);
    s8v al01 = *(const s8v*)(Al + ao + 32);
    s8v al10 = *(const s8v*)(Al + ao + 16*64);
    s8v al11 = *(const s8v*)(Al + ao + 16*64 + 32);
    int bo = (lane & 15) * 64 + (lane >> 4) * 8;
    for (int n = 0; n < 12; n++) {
      s8v bh0 = *(const s8v*)(WqH + bo + n*1024);
      s8v bh1 = *(const s8v*)(WqH + bo + n*1024 + 32);
      s8v bl0 = *(const s8v*)(WqL + bo + n*1024);
      s8v bl1 = *(const s8v*)(WqL + bo + n*1024 + 32);
      f32x4 acc0 = {}, acc1 = {};
      acc0 = __builtin_amdgcn_mfma_f32_16x16x32_bf16(ah00, bh0, acc0, 0,0,0);
      acc0 = __builtin_amdgcn_mfma_f32_16x16x32_bf16(ah01, bh1, acc0, 0,0,0);
      acc0 = __builtin_amdgcn_mfma_f32_16x16x32_bf16(al00, bh0, acc0, 0,0,0);
      acc0 = __builtin_amdgcn_mfma_f32_16x16x32_bf16(al01, bh1, acc0, 0,0,0);
      acc0 = __builtin_amdgcn_mfma_f32_16x16x32_bf16(ah00, bl0, acc0, 0,0,0);
      acc0 = __builtin_amdgcn_mfma_f32_16x16x32_bf16(ah01, bl1, acc0, 0,0,0);
      acc1 = __builtin_amdgcn_mfma_f32_16x16x32_bf16(ah10, bh0, acc1, 0,0,0);
      acc1 = __builtin_amdgcn_mfma_f32_16x16x32_bf16(ah11, bh1, acc1, 0,0,0);
      acc1 = __builtin_amdgcn_mfma_f32_16x16x32_bf16(al10, bh0, acc1, 0,0,0);
      acc1 = __builtin_amdgcn_mfma_f32_16x16x32_bf16(al11, bh1, acc1, 0,0,0);
      acc1 = __builtin_amdgcn_mfma_f32_16x16x32_bf16(ah10, bl0, acc1, 0,0,0);
      acc1 = __builtin_amdgcn_mfma_f32_16x16x32_bf16(ah11, bl1, acc1, 0,0,0);
      int j = n*16 + (lane & 15);
      int ch = j >> 6, jj = j & 63;
      float bv = attn_b[j];
#pragma unroll
      for (int r = 0; r < 4; r++) {
        int m0 = w*32 + (lane>>4)*4 + r;
        qkv[((size_t)(b*3 + ch)*128 + m0)*64 + jj] = acc0[r] + bv;
        qkv[((size_t)(b*3 + ch)*128 + m0 + 16)*64 + jj] = acc1[r] + bv;
      }
    }
  } else {                   // logits for step t-1 (single bf16)
    if (t == 0) return;
    int jt = bid - 128;
    f32x4 acc[4] = {};
    const short* B = Wp16 + (size_t)(jt*64 + w*16) * 1280;
    gemm4<1280, 40>(pob16, B, acc, lane);
    int j = jt*64 + w*16 + (lane & 15);
    float bv = b_proj[j];
#pragma unroll
    for (int ms = 0; ms < 4; ms++)
#pragma unroll
      for (int r = 0; r < 4; r++) {
        int b = ms*16 + (lane>>4)*4 + r;
        outs[((size_t)b*256 + (t-1))*1024 + j] = acc[ms][r] + bv;
      }
  }
}

// ---------- k2: attn(256 blocks) | lstm(64 blocks) ----------
__global__ __launch_bounds__(256) void k2(
    float* __restrict__ mem, const float* __restrict__ qkv,
    const float* __restrict__ attn_ow, const float* __restrict__ attn_ob,
    const float* __restrict__ l1w, const float* __restrict__ l1b,
    const float* __restrict__ l2w, const float* __restrict__ l2b,
    const float* __restrict__ tn1g, const float* __restrict__ tn1b,
    const float* __restrict__ tn2g, const float* __restrict__ tn2b,
    const float* __restrict__ gates, const float* __restrict__ b_ih,
    const float* __restrict__ b_hh, float* __restrict__ cbuf,
    float* __restrict__ hbuf, short* __restrict__ inbH, short* __restrict__ inbL,
    const float* __restrict__ cn_g, const float* __restrict__ cn_b,
    float* __restrict__ hn, short* __restrict__ hnH, short* __restrict__ hnL)
{
  __shared__ float P[28544];
  int bid = blockIdx.x, tid = threadIdx.x;
  int lane = tid & 63, wid = tid >> 6;
  if (bid >= 256) {
    // ---- LSTM ----
    __shared__ float rs[4], rq[4];
    int b = bid - 256;
    float hv[4]; float s = 0.f, sq = 0.f;
#pragma unroll
    for (int i = 0; i < 4; i++) {
      int u = tid + i * 256;
      float g4[4];
#pragma unroll
      for (int q = 0; q < 4; q++)
        g4[q] = b_ih[q*1024+u] + b_hh[q*1024+u] + gates[b*4096 + q*1024 + u];
      float cn = sigm(g4[1]) * cbuf[b*1024+u] + sigm(g4[0]) * tanhf(g4[2]);
      float hh = sigm(g4[3]) * tanhf(cn);
      cbuf[b*1024+u] = cn;
      hbuf[b*1024+u] = hh;
      storesplit(hh, inbH, inbL, b*1792 + 768 + u);
      hv[i] = hh; s += hh; sq += hh*hh;
    }
    s = wsum(s); sq = wsum(sq);
    if (lane == 0) { rs[wid] = s; rq[wid] = sq; }
    __syncthreads();
    float ts = rs[0]+rs[1]+rs[2]+rs[3], tq = rq[0]+rq[1]+rq[2]+rq[3];
    float mu = ts / 1024.f, var = tq / 1024.f - mu*mu;
    float rstd = rsqrtf(var + 1e-5f);
#pragma unroll
    for (int i = 0; i < 4; i++) {
      int u = tid + i * 256;
      float v = (hv[i] - mu) * rstd * cn_g[u] + cn_b[u];
      hn[b*1024 + u] = v;
      storesplit(v, hnH, hnL, b*1024 + u);
    }
    return;
  }
  // ---- attention + proj + LN1 + FF + LN2 (in-place mem) ----
  float* sK  = P;
  float* sV  = P + 8704;
  float* sX  = P + 17152;
  float* sM  = P + 19328;
  float* sO  = P + 21504;
  float* sS  = P + 23680;
  float* sRed= P + 28032;
  int b = bid & 63, mt = bid >> 6;
  int m0 = mt * 32;
  const float* qb = qkv + (size_t)b*3*8192;
  for (int i = tid*4; i < 8192; i += 1024) {
    *(float4*)&sK[i] = *(const float4*)&qb[8192 + i];
    *(float4*)&sV[i] = *(const float4*)&qb[16384 + i];
  }
  for (int i = tid*4; i < 2048; i += 1024) {
    int m = i >> 6, s = i & 63;
    *(float4*)&sX[m*68+s] = *(const float4*)&qb[m0*64 + i];
    *(float4*)&sM[m*68+s] = *(const float4*)&mem[(size_t)b*8192 + m0*64 + i];
  }
  __syncthreads();
  int m = tid >> 3, hd = (tid >> 1) & 3, half = tid & 1;
  const float* qp = sX + m*68 + hd*16;
  float4 q0 = *(const float4*)(qp),   q1 = *(const float4*)(qp+4);
  float4 q2 = *(const float4*)(qp+8), q3 = *(const float4*)(qp+12);
  int kmb = half * 64;
  float mx = -1e30f;
#pragma unroll 4
  for (int kk = 0; kk < 64; kk++) {
    const float* kp = sK + (kmb+kk)*64 + hd*16;
    float sc = dot4(q0, *(const float4*)kp)     + dot4(q1, *(const float4*)(kp+4))
             + dot4(q2, *(const float4*)(kp+8)) + dot4(q3, *(const float4*)(kp+12));
    mx = fmaxf(mx, sc * 0.25f);
  }
  float4 o0 = {0,0,0,0}, o1 = {0,0,0,0}, o2 = {0,0,0,0}, o3 = {0,0,0,0};
  float sum = 0.f;
#pragma unroll 4
  for (int kk = 0; kk < 64; kk++) {
    const float* kp = sK + (kmb+kk)*64 + hd*16;
    float sc = dot4(q0, *(const float4*)kp)     + dot4(q1, *(const float4*)(kp+4))
             + dot4(q2, *(const float4*)(kp+8)) + dot4(q3, *(const float4*)(kp+12));
    float e = expf(sc * 0.25f - mx);
    sum += e;
    const float* vp = sV + (kmb+kk)*64 + hd*16;
    float4 v0 = *(const float4*)vp,     v1 = *(const float4*)(vp+4);
    float4 v2 = *(const float4*)(vp+8), v3 = *(const float4*)(vp+12);
    o0.x += e*v0.x; o0.y += e*v0.y; o0.z += e*v0.z; o0.w += e*v0.w;
    o1.x += e*v1.x; o1.y += e*v1.y; o1.z += e*v1.z; o1.w += e*v1.w;
    o2.x += e*v2.x; o2.y += e*v2.y; o2.z += e*v2.z; o2.w += e*v2.w;
    o3.x += e*v3.x; o3.y += e*v3.y; o3.z += e*v3.z; o3.w += e*v3.w;
  }
  {
    float* pp = sS + tid*17;
    pp[0]=o0.x; pp[1]=o0.y; pp[2]=o0.z; pp[3]=o0.w;
    pp[4]=o1.x; pp[5]=o1.y; pp[6]=o1.z; pp[7]=o1.w;
    pp[8]=o2.x; pp[9]=o2.y; pp[10]=o2.z; pp[11]=o2.w;
    pp[12]=o3.x; pp[13]=o3.y; pp[14]=o3.z; pp[15]=o3.w;
    sRed[tid] = mx; sRed[256+tid] = sum;
  }
  __syncthreads();
  if (half == 0) {
    float mx1 = sRed[tid+1], sm1 = sRed[256+tid+1];
    float M = fmaxf(mx, mx1);
    float e0 = expf(mx - M), e1 = expf(mx1 - M);
    float inv = 1.0f / (sum*e0 + sm1*e1);
    const float* pq = sS + (tid+1)*17;
    float* op = sO + m*68 + hd*16;
    op[0]  = (o0.x*e0 + pq[0]*e1)*inv;  op[1]  = (o0.y*e0 + pq[1]*e1)*inv;
    op[2]  = (o0.z*e0 + pq[2]*e1)*inv;  op[3]  = (o0.w*e0 + pq[3]*e1)*inv;
    op[4]  = (o1.x*e0 + pq[4]*e1)*inv;  op[5]  = (o1.y*e0 + pq[5]*e1)*inv;
    op[6]  = (o1.z*e0 + pq[6]*e1)*inv;  op[7]  = (o1.w*e0 + pq[7]*e1)*inv;
    op[8]  = (o2.x*e0 + pq[8]*e1)*inv;  op[9]  = (o2.y*e0 + pq[9]*e1)*inv;
    op[10] = (o2.z*e0 + pq[10]*e1)*inv; op[11] = (o2.w*e0 + pq[11]*e1)*inv;
    op[12] = (o3.x*e0 + pq[12]*e1)*inv; op[13] = (o3.y*e0 + pq[13]*e1)*inv;
    op[14] = (o3.z*e0 + pq[14]*e1)*inv; op[15] = (o3.w*e0 + pq[15]*e1)*inv;
  }
  __syncthreads();
  for (int idx = tid; idx < 4096; idx += 256) {
    int j = idx >> 6, s = idx & 63;
    sS[j*68 + s] = attn_ow[idx];
  }
  __syncthreads();
  {
    int mm = tid >> 3, jset = tid & 7;
    float4 orow[16];
#pragma unroll
    for (int r = 0; r < 16; r++) orow[r] = *(const float4*)&sO[mm*68 + r*4];
#pragma unroll
    for (int i = 0; i < 8; i++) {
      int j = jset + 8*i;
      const float* wr = sS + j*68;
      float acc = attn_ob[j];
#pragma unroll
      for (int r = 0; r < 16; r++) acc += dot4(orow[r], *(const float4*)&wr[r*4]);
      sM[mm*68 + j] += acc;
    }
  }
  __syncthreads();
  for (int r = wid; r < 32; r += 4) {
    float v = sM[r*68 + lane];
    float ssum = wsum(v), ssq = wsum(v*v);
    float mu = ssum*(1.f/64), var = ssq*(1.f/64) - mu*mu;
    sX[r*68+lane] = (v - mu)*rsqrtf(var+1e-5f)*tn1g[lane] + tn1b[lane];
  }
  for (int idx = tid; idx < 8192; idx += 256) {
    int f = idx >> 6, s = idx & 63;
    sK[f*68 + s] = l1w[idx];
  }
  for (int idx = tid; idx < 8192; idx += 256) {
    int j = idx >> 7, s = idx & 127;
    sV[j*132 + s] = l2w[idx];
  }
  __syncthreads();
  {
    int mm = tid >> 3, fs = tid & 7;
    float4 xr[16];
#pragma unroll
    for (int r = 0; r < 16; r++) xr[r] = *(const float4*)&sX[mm*68 + r*4];
#pragma unroll 4
    for (int i = 0; i < 16; i++) {
      int f = fs + 8*i;
      const float* wr = sK + f*68;
      float acc = l1b[f];
#pragma unroll
      for (int r = 0; r < 16; r++) acc += dot4(xr[r], *(const float4*)&wr[r*4]);
      sS[mm*132 + f] = 0.5f*acc*(1.0f + erff(acc*0.70710678118654752f));
    }
  }
  __syncthreads();
  {
    int mm = tid >> 3, jset = tid & 7;
    float acc6[8];
#pragma unroll
    for (int i = 0; i < 8; i++) acc6[i] = sX[mm*68 + jset + 8*i] + l2b[jset + 8*i];
#pragma unroll
    for (int h = 0; h < 2; h++) {
      float4 fr[16];
#pragma unroll
      for (int r = 0; r < 16; r++) fr[r] = *(const float4*)&sS[mm*132 + h*64 + r*4];
#pragma unroll
      for (int i = 0; i < 8; i++) {
        int j = jset + 8*i;
        const float* wr = sV + j*132 + h*64;
        float a = 0.f;
#pragma unroll
        for (int r = 0; r < 16; r++) a += dot4(fr[r], *(const float4*)&wr[r*4]);
        acc6[i] += a;
      }
    }
#pragma unroll
    for (int i = 0; i < 8; i++) sO[mm*68 + jset + 8*i] = acc6[i];
  }
  __syncthreads();
  for (int r = wid; r < 32; r += 4) {
    float v = sO[r*68 + lane];
    float ssum = wsum(v), ssq = wsum(v*v);
    float mu = ssum*(1.f/64), var = ssq*(1.f/64) - mu*mu;
    mem[(size_t)b*8192 + (m0+r)*64 + lane] =
        (v - mu)*rsqrtf(var+1e-5f)*tn2g[lane] + tn2b[lane];
  }
}

// ---------- k3: heads via split MFMA, grid 13, 256 thr ----------
__global__ __launch_bounds__(256) void k3(
    const short* __restrict__ hnH, const short* __restrict__ hnL,
    const short* __restrict__ WhH, const short* __restrict__ WhL,
    const float* __restrict__ b_rk, const float* __restrict__ b_wk,
    const float* __restrict__ b_ev, const float* __restrict__ b_ws,
    const float* __restrict__ rkn_g, const float* __restrict__ rkn_b,
    const float* __restrict__ wkn_g, const float* __restrict__ wkn_b,
    float* __restrict__ rkn, float* __restrict__ wkn,
    float* __restrict__ evb, float* __restrict__ ws4)
{
  __shared__ float sC[64*68];
  int jt = blockIdx.x, tid = threadIdx.x, lane = tid & 63, w = tid >> 6;
  f32x4 acc[4] = {};
  size_t boff = (size_t)(jt*64 + w*16) * 1024;
  gemm4s<1024, 32>(hnH, hnL, WhH + boff, WhL + boff, acc, lane);
  int n = jt*64 + w*16 + (lane & 15);
  if (jt < 8) {
    const float* bias = (jt < 4) ? b_rk : b_wk;
    float bv = bias[n - ((jt < 4) ? 0 : 256)];
#pragma unroll
    for (int ms = 0; ms < 4; ms++)
#pragma unroll
      for (int r = 0; r < 4; r++) {
        int bb = ms*16 + (lane>>4)*4 + r;
        sC[bb*68 + w*16 + (lane & 15)] = acc[ms][r] + bv;
      }
    __syncthreads();
    int head = jt & 3;
    float* dst = (jt < 4) ? rkn : wkn;
    const float* gg = (jt < 4) ? rkn_g : wkn_g;
    const float* bb2 = (jt < 4) ? rkn_b : wkn_b;
    for (int i = 0; i < 16; i++) {
      int bb = w*16 + i;
      float v = sC[bb*68 + lane];
      float ssum = wsum(v), ssq = wsum(v*v);
      float mu = ssum*(1.f/64), var = ssq*(1.f/64) - mu*mu;
      dst[bb*256 + head*64 + lane] = (v - mu)*rsqrtf(var+1e-5f)*gg[lane] + bb2[lane];
    }
  } else if (jt < 12) {
    float bv = b_ev[n - 512];
#pragma unroll
    for (int ms = 0; ms < 4; ms++)
#pragma unroll
      for (int r = 0; r < 4; r++) {
        int bb = ms*16 + (lane>>4)*4 + r;
        evb[bb*256 + (n - 512)] = sigm(acc[ms][r] + bv);
      }
  } else {
    if (n < 772) {
      float bv = b_ws[n - 768];
#pragma unroll
      for (int ms = 0; ms < 4; ms++)
#pragma unroll
        for (int r = 0; r < 4; r++) {
          int bb = ms*16 + (lane>>4)*4 + r;
          ws4[bb*4 + (n - 768)] = sigm(acc[ms][r] + bv);
        }
    }
  }
}

// ---------- k4: NTM addressing + mem update + output LN + next xin ----------
__global__ __launch_bounds__(256) void k4(
    float* __restrict__ mem, short* __restrict__ membH, short* __restrict__ membL,
    const float* __restrict__ rkn, const float* __restrict__ wkn,
    const float* __restrict__ evb, const float* __restrict__ ws4,
    const float* __restrict__ hn,
    const float* __restrict__ mng, const float* __restrict__ mnb,
    const float* __restrict__ pog, const float* __restrict__ pob,
    const float* __restrict__ x_emb, const float* __restrict__ in_g,
    const float* __restrict__ in_b,
    short* __restrict__ inbH, short* __restrict__ inbL,
    short* __restrict__ pob16, int tnext)
{
  __shared__ float sMT[8192];
  __shared__ float sMN[128*65];
  __shared__ float sRk[256], sWk[256], sEv[256], sWs[4];
  __shared__ float sRw[512], sWw[512], sRc[256];
  __shared__ float rs[4], rq[4];
  int b = blockIdx.x, tid = threadIdx.x, lane = tid & 63, wid = tid >> 6;
  for (int i = tid*4; i < 8192; i += 1024)
    *(float4*)&sMT[i] = *(const float4*)&mem[(size_t)b*8192 + i];
  sRk[tid] = rkn[b*256 + tid]; sWk[tid] = wkn[b*256 + tid]; sEv[tid] = evb[b*256 + tid];
  if (tid < 4) sWs[tid] = ws4[b*4 + tid];
  __syncthreads();
  for (int r = wid; r < 128; r += 4) {
    float v = sMT[r*64 + lane];
    float ssum = wsum(v), ssq = wsum(v*v);
    float mu = ssum*(1.f/64), var = ssq*(1.f/64) - mu*mu;
    sMN[r*65 + lane] = (v - mu)*rsqrtf(var+1e-5f)*mng[lane] + mnb[lane];
  }
  __syncthreads();
#pragma unroll
  for (int q = 0; q < 4; q++) {
    int idx = tid + q*256;
    int which = idx >> 9;
    int n = (idx >> 7) & 3, m = idx & 127;
    const float* key = (which ? sWk : sRk) + n*64;
    const float* mr = sMN + m*65;
    float acc = 0.f;
#pragma unroll 8
    for (int k = 0; k < 64; k++) acc += key[k]*mr[k];
    (which ? sWw : sRw)[n*128 + m] = acc;
  }
  __syncthreads();
  for (int r = wid; r < 8; r += 4) {
    float* row = (r < 4) ? (sRw + r*128) : (sWw + (r-4)*128);
    float a0 = row[lane], a1 = row[lane+64];
    float mx = fmaxf(a0, a1);
#pragma unroll
    for (int o = 32; o > 0; o >>= 1) mx = fmaxf(mx, __shfl_xor(mx, o, 64));
    float e0 = expf(a0 - mx), e1 = expf(a1 - mx);
    float inv = 1.0f / wsum(e0 + e1);
    row[lane] = e0*inv; row[lane+64] = e1*inv;
  }
  __syncthreads();
  {
    int n = tid >> 6, s2 = tid & 63;
    float acc = 0.f;
    for (int mm = 0; mm < 128; mm++) acc += sRw[n*128 + mm] * sMT[mm*64 + s2];
    sRc[tid] = acc;
  }
  __syncthreads();
  for (int idx = tid; idx < 8192; idx += 256) {
    int mm = idx >> 6, s2 = idx & 63;
    float er = 0.f, ad = 0.f;
#pragma unroll
    for (int n = 0; n < 4; n++) {
      float w = sWw[n*128 + mm];
      er += w * sEv[n*64 + s2];
      ad += w * sWs[n] * sWk[n*64 + s2];
    }
    float val = sMT[idx]*(1.0f - er) + ad;
    mem[(size_t)b*8192 + idx] = val;
    storesplit(val, membH, membL, (size_t)b*8192 + idx);
  }
  float v5[5]; float s = 0.f, sq = 0.f;
#pragma unroll
  for (int i = 0; i < 5; i++) {
    int k = tid + i*256;
    float v = (k < 1024) ? hn[b*1024 + k] : sRc[k-1024];
    v5[i] = v; s += v; sq += v*v;
  }
  s = wsum(s); sq = wsum(sq);
  if (lane == 0) { rs[wid] = s; rq[wid] = sq; }
  __syncthreads();
  {
    float ts = rs[0]+rs[1]+rs[2]+rs[3], tq = rq[0]+rq[1]+rq[2]+rq[3];
    float mu = ts/1280.f, var = tq/1280.f - mu*mu;
    float rstd = rsqrtf(var + 1e-5f);
#pragma unroll
    for (int i = 0; i < 5; i++) {
      int k = tid + i*256;
      pob16[b*1280 + k] = f2bf((v5[i] - mu)*rstd*pog[k] + pob[k]);
    }
  }
  if (tnext < 256) {
    __syncthreads();
    float v3[3]; float s2 = 0.f, q2 = 0.f;
#pragma unroll
    for (int i = 0; i < 3; i++) {
      int k = tid + i*256;
      float v = (k < 512) ? x_emb[((size_t)b*256 + tnext)*512 + k] : sRc[k-512];
      v3[i] = v; s2 += v; q2 += v*v;
    }
    s2 = wsum(s2); q2 = wsum(q2);
    if (lane == 0) { rs[wid] = s2; rq[wid] = q2; }
    __syncthreads();
    float ts = rs[0]+rs[1]+rs[2]+rs[3], tq = rq[0]+rq[1]+rq[2]+rq[3];
    float mu = ts/768.f, var = tq/768.f - mu*mu;
    float rstd = rsqrtf(var + 1e-5f);
#pragma unroll
    for (int i = 0; i < 3; i++) {
      int k = tid + i*256;
      storesplit((v3[i] - mu)*rstd*in_g[k] + in_b[k], inbH, inbL, b*1792 + k);
    }
  }
}

// ---------- final copy ----------
__global__ void k_final(const float* __restrict__ mem, const float* __restrict__ hbuf,
                        const float* __restrict__ cbuf, float* __restrict__ out)
{
  int i = blockIdx.x * 256 + threadIdx.x;
  if (i < 524288) out[16777216 + i] = mem[i];
  if (i < 65536) {
    out[17301504 + i] = hbuf[i];
    out[17367040 + i] = cbuf[i];
  }
}

extern "C" void kernel_launch(void* const* d_in, const int* in_sizes, int n_in,
                              void* d_out, int out_size, void* d_ws, size_t ws_size,
                              hipStream_t stream) {
  const float* x_emb  = (const float*)d_in[0];
  const float* in_g   = (const float*)d_in[1];
  const float* in_b   = (const float*)d_in[2];
  const float* W_ih   = (const float*)d_in[3];
  const float* W_hh   = (const float*)d_in[4];
  const float* b_ih   = (const float*)d_in[5];
  const float* b_hh   = (const float*)d_in[6];
  const float* cn_g   = (const float*)d_in[7];
  const float* cn_b   = (const float*)d_in[8];
  const float* W_rk   = (const float*)d_in[9];
  const float* b_rk   = (const float*)d_in[10];
  const float* W_wk   = (const float*)d_in[11];
  const float* b_wk   = (const float*)d_in[12];
  const float* W_ws   = (const float*)d_in[13];
  const float* b_ws   = (const float*)d_in[14];
  const float* W_ev   = (const float*)d_in[15];
  const float* b_ev   = (const float*)d_in[16];
  const float* attn_w = (const float*)d_in[17];
  const float* attn_b = (const float*)d_in[18];
  const float* attn_ow= (const float*)d_in[19];
  const float* attn_ob= (const float*)d_in[20];
  const float* l1_w   = (const float*)d_in[21];
  const float* l1_b   = (const float*)d_in[22];
  const float* l2_w   = (const float*)d_in[23];
  const float* l2_b   = (const float*)d_in[24];
  const float* tn1_g  = (const float*)d_in[25];
  const float* tn1_b  = (const float*)d_in[26];
  const float* tn2_g  = (const float*)d_in[27];
  const float* tn2_b  = (const float*)d_in[28];
  const float* rkn_g  = (const float*)d_in[29];
  const float* rkn_b  = (const float*)d_in[30];
  const float* wkn_g  = (const float*)d_in[31];
  const float* wkn_b  = (const float*)d_in[32];
  const float* mn_g   = (const float*)d_in[33];
  const float* mn_b   = (const float*)d_in[34];
  const float* po_g   = (const float*)d_in[35];
  const float* po_b   = (const float*)d_in[36];
  const float* W_proj = (const float*)d_in[37];
  const float* b_proj = (const float*)d_in[38];

  float* ws = (float*)d_ws;
  float* mem   = ws;                  // 524288
  float* cbuf  = ws + 524288;         // 65536
  float* hbuf  = ws + 589824;         // 65536
  float* hn    = ws + 655360;         // 65536
  float* gates = ws + 720896;         // 262144
  float* rkn   = ws + 983040;         // 16384
  float* wkn   = ws + 999424;         // 16384
  float* evb   = ws + 1015808;        // 16384
  float* ws4   = ws + 1032192;        // 256
  float* qkvb  = ws + 1032448;        // 1572864 -> end 2605312 floats
  short* sb    = (short*)(ws + 2605312);
  short* inbH  = sb;                  // 114688
  short* inbL  = sb + 114688;         // 114688
  short* membH = sb + 229376;         // 524288
  short* membL = sb + 753664;         // 524288
  short* hnH   = sb + 1277952;        // 65536
  short* hnL   = sb + 1343488;        // 65536
  short* pob16 = sb + 1409024;        // 81920
  short* WgH   = sb + 1490944;        // 7340032
  short* WgL   = sb + 8830976;        // 7340032
  short* WhH   = sb + 16171008;       // 851968
  short* WhL   = sb + 17022976;       // 851968
  short* WqH   = sb + 17874944;       // 12288
  short* WqL   = sb + 17887232;       // 12288
  short* Wp16  = sb + 17899520;       // 1310720 -> end 19210240 shorts

  // zero recurrent fp32 state (mem, cbuf, hbuf) and bf16 shadows (inb, memb)
  hipMemsetAsync(ws, 0, 655360 * sizeof(float), stream);
  hipMemsetAsync(sb, 0, 1277952 * sizeof(short), stream);

  // one-time weight conversion
  kprep_g<<<dim3(7, 4096), 256, 0, stream>>>(W_ih, W_hh, WgH, WgL);
  kprep_p<<<dim3(5, 1024), 256, 0, stream>>>(W_proj, Wp16);
  kprep_h<<<dim3(4, 832), 256, 0, stream>>>(W_rk, W_wk, W_ev, W_ws, WhH, WhL);
  kprep_q<<<dim3(192), 64, 0, stream>>>(attn_w, WqH, WqL);
  k_prep0<<<64, 256, 0, stream>>>(x_emb, in_g, in_b, inbH, inbL);

  float* outs = (float*)d_out;
  for (int t = 0; t < 256; t++) {
    k1<<<144, 256, 0, stream>>>(inbH, inbL, WgH, WgL, membH, membL, WqH, WqL,
                                attn_b, pob16, Wp16, b_proj, gates, qkvb, outs, t);
    k2<<<320, 256, 0, stream>>>(mem, qkvb, attn_ow, attn_ob,
                                l1_w, l1_b, l2_w, l2_b,
                                tn1_g, tn1_b, tn2_g, tn2_b,
                                gates, b_ih, b_hh, cbuf, hbuf, inbH, inbL,
                                cn_g, cn_b, hn, hnH, hnL);
    k3<<<13, 256, 0, stream>>>(hnH, hnL, WhH, WhL, b_rk, b_wk, b_ev, b_ws,
                               rkn_g, rkn_b, wkn_g, wkn_b,
                               rkn, wkn, evb, ws4);
    k4<<<64, 256, 0, stream>>>(mem, membH, membL, rkn, wkn, evb, ws4, hn,
                               mn_g, mn_b, po_g, po_b,
                               x_emb, in_g, in_b, inbH, inbL, pob16, t+1);
  }
  // last-step logits
  k1<<<144, 256, 0, stream>>>(inbH, inbL, WgH, WgL, membH, membL, WqH, WqL,
                              attn_b, pob16, Wp16, b_proj, gates, qkvb, outs, 256);
  k_final<<<2048, 256, 0, stream>>>(mem, hbuf, cbuf, (float*)d_out);
}